// Round 5
// baseline (686.423 us; speedup 1.0000x reference)
//
#include <hip/hip_runtime.h>

#define NN 32      // nodes
#define FF 64      // GAT out features
#define HH 128     // LSTM hidden
#define G4 512     // 4*H
#define BB 32      // batch
#define TT 512     // time steps
#define ET 128     // 96 edges + 32 self loops
#define NPOS (BB*TT)

typedef float f2 __attribute__((ext_vector_type(2)));
typedef float f4 __attribute__((ext_vector_type(4)));

__device__ __forceinline__ float frcp(float x) { return __builtin_amdgcn_rcpf(x); }
__device__ __forceinline__ float sigm(float x) { return frcp(1.f + __expf(-x)); }
__device__ __forceinline__ float tanh_fast(float x) { return 1.f - 2.f * frcp(1.f + __expf(2.f * x)); }

// raw barrier: LDS drain only — does NOT drain vmcnt, so global prefetches
// issued before it stay in flight (unlike __syncthreads, which drains vmcnt(0))
#define LDS_BARRIER() asm volatile("s_waitcnt lgkmcnt(0)\n\ts_barrier" ::: "memory")

// ---------------- prep: fold GAT linear into LSTM input weights ----------------
__global__ __launch_bounds__(512) void prep_kernel(const float* __restrict__ w_gat,
                                                   const float* __restrict__ b_gat,
                                                   const float* __restrict__ W_ih,
                                                   float* __restrict__ W_eff,
                                                   float* __restrict__ biasp) {
  int j = threadIdx.x;
  int n = blockIdx.x;
  float accw = 0.f, accb = 0.f;
#pragma unroll 8
  for (int f = 0; f < FF; ++f) {
    float wv = W_ih[(n * FF + f) * G4 + j];
    accw = fmaf(w_gat[f], wv, accw);
    accb = fmaf(b_gat[f], wv, accb);
  }
  W_eff[n * G4 + j] = accw;
  biasp[n * G4 + j] = accb;
}

// bias reduce + attention scalars + edge count-sort by dst
__global__ __launch_bounds__(512) void prep2_kernel(const float* __restrict__ biasp,
                                                    const float* __restrict__ b_ih,
                                                    const float* __restrict__ b_hh,
                                                    const float* __restrict__ w_gat,
                                                    const float* __restrict__ att_src,
                                                    const float* __restrict__ att_dst,
                                                    const int* __restrict__ ei,
                                                    float* __restrict__ bias_eff,
                                                    float* __restrict__ scal,
                                                    int* __restrict__ srt_g,
                                                    int* __restrict__ off_g) {
  __shared__ int cnt[NN];
  __shared__ int off[NN + 1];
  __shared__ int srt[ET];
  int j = threadIdx.x;
  if (j < NN) cnt[j] = 0;
  float acc = b_ih[j] + b_hh[j];
#pragma unroll
  for (int n = 0; n < NN; ++n) acc += biasp[n * G4 + j];
  bias_eff[j] = acc;
  if (j == 0) {
    float cs = 0.f, cd = 0.f;
    for (int f = 0; f < FF; ++f) {
      cs = fmaf(w_gat[f], att_src[f], cs);
      cd = fmaf(w_gat[f], att_dst[f], cd);
    }
    scal[0] = cs;
    scal[1] = cd;
  }
  __syncthreads();
  int s = 0, d = 0, tk = 0;
  if (j < ET) {
    if (j < 96) { s = ei[j]; d = ei[96 + j]; }
    else { s = j - 96; d = j - 96; }
    tk = atomicAdd(&cnt[d], 1);
  }
  __syncthreads();
  if (j == 0) {
    off[0] = 0;
    for (int n = 0; n < NN; ++n) off[n + 1] = off[n] + cnt[n];
  }
  __syncthreads();
  if (j < ET) srt[off[d] + tk] = s;
  __syncthreads();
  if (j < ET) srt_g[j] = srt[j];
  if (j < NN + 1) off_g[j] = off[j];
}

// ---------------- fused GAT + xw: 8 positions per 256-thread block ----------------
// Edges pre-sorted by dst: lane n only walks its own segment (~5 edges) instead
// of all 128 with predication.
__global__ __launch_bounds__(256) void gatxw_kernel(const float* __restrict__ x_seq,
                                                    const int* __restrict__ srt_g,
                                                    const int* __restrict__ off_g,
                                                    const float* __restrict__ scal,
                                                    const float* __restrict__ W_eff,
                                                    const float* __restrict__ bias_eff,
                                                    float* __restrict__ xw) {
  __shared__ int srt[ET];
  __shared__ int offs[NN + 1];
  __shared__ float xs[8 * 32];
  __shared__ float sl[8 * 32];
  int tid = threadIdx.x;
  int posbase = blockIdx.x * 8;
  float we0[NN], we1[NN];
#pragma unroll
  for (int nn = 0; nn < NN; ++nn) {
    we0[nn] = W_eff[nn * G4 + tid];
    we1[nn] = W_eff[nn * G4 + 256 + tid];
  }
  float b0 = bias_eff[tid], b1 = bias_eff[256 + tid];
  if (tid < ET) srt[tid] = srt_g[tid];
  if (tid < NN + 1) offs[tid] = off_g[tid];
  int p = tid >> 5, n = tid & 31;
  xs[tid] = x_seq[posbase * NN + tid];  // coalesced
  __syncthreads();
  float cs = scal[0], cd = scal[1];
  int base = p * 32;
  int e0 = offs[n], e1 = offs[n + 1];
  float xn = xs[base + n];
  float cdxn = cd * xn;
  // pass 1: max over this dst's segment
  float m = -3.0e38f;
  for (int e = e0; e < e1; ++e) {
    float ev = fmaf(cs, xs[base + srt[e]], cdxn);
    ev = ev > 0.f ? ev : 0.2f * ev;  // LeakyReLU(0.2)
    m = fmaxf(m, ev);
  }
  // pass 2: softmax-weighted sum of x[src]
  float z = 0.f, sa = 0.f;
  for (int e = e0; e < e1; ++e) {
    float xsv = xs[base + srt[e]];
    float ev = fmaf(cs, xsv, cdxn);
    ev = ev > 0.f ? ev : 0.2f * ev;
    float ex = __expf(ev - m);
    z += ex;
    sa = fmaf(ex, xsv, sa);
  }
  sl[p * 32 + n] = sa * frcp(z);
  __syncthreads();
  for (int pp = 0; pp < 8; ++pp) {
    const float4* sp = (const float4*)&sl[pp * 32];
    float a0 = b0, a1 = b1;
#pragma unroll
    for (int q = 0; q < 8; ++q) {
      float4 sv = sp[q];
      a0 = fmaf(sv.x, we0[4 * q], a0);
      a0 = fmaf(sv.y, we0[4 * q + 1], a0);
      a0 = fmaf(sv.z, we0[4 * q + 2], a0);
      a0 = fmaf(sv.w, we0[4 * q + 3], a0);
      a1 = fmaf(sv.x, we1[4 * q], a1);
      a1 = fmaf(sv.y, we1[4 * q + 1], a1);
      a1 = fmaf(sv.z, we1[4 * q + 2], a1);
      a1 = fmaf(sv.w, we1[4 * q + 3], a1);
    }
    size_t row = (size_t)(posbase + pp) * G4;
    xw[row + tid] = a0;
    xw[row + 256 + tid] = a1;
  }
}

// ---------------- LSTM scan ----------------
// R1-R4 lesson: the wall was LDS broadcast-return bandwidth (every thread read
// all 128 h => 256 KB/step/CU ~ 2100 cyc). Here: 256 threads, thread (r,k-half)
// owns ALL 4 gate columns of row r for its half of K:
//  - LDS h traffic /4 (each thread reads 64 h = 256 B -> 64 KB/step)
//  - h-update thread-local (no act[] roundtrip), pair-reduce via shfl_xor(1)
//  - v_pk_fma_f32 halves FMA issue
//  - double-buffered h, ONE lgkm-only barrier per step
//  - 256 weights/thread pinned via asm; waves_per_eu(1,1) => 512-reg budget,
//    occupancy target 1 => no remat motive
__global__ __attribute__((amdgpu_flat_work_group_size(256, 256), amdgpu_waves_per_eu(1, 1)))
void lstm_kernel(const float* __restrict__ xw,
                 const float* __restrict__ W_hh,
                 const float* __restrict__ W_fc,
                 const float* __restrict__ b_fc,
                 float* __restrict__ out) {
  __shared__ float hbufA[HH];
  __shared__ float hbufB[HH];
  int b = blockIdx.x, tid = threadIdx.x;
  int r = tid >> 1;        // gate row 0..127
  int ks = tid & 1;        // k-half
  // 256 weights: w_g[k2] = (W_hh[k][col_g], W_hh[k+1][col_g]), k = ks*64+2*k2
  f2 w0[32], w1[32], w2[32], w3[32];
  {
    const float* wb = W_hh + (size_t)(ks * 64) * G4 + r;
#pragma unroll
    for (int k2 = 0; k2 < 32; ++k2) {
      const float* wk = wb + (2 * k2) * G4;
      w0[k2] = f2{wk[0], wk[G4]};
      w1[k2] = f2{wk[128], wk[G4 + 128]};
      w2[k2] = f2{wk[256], wk[G4 + 256]};
      w3[k2] = f2{wk[384], wk[G4 + 384]};
    }
  }
#pragma unroll
  for (int k2 = 0; k2 < 32; ++k2)
    asm volatile("" : "+v"(w0[k2]), "+v"(w1[k2]), "+v"(w2[k2]), "+v"(w3[k2]));
  if (tid < HH) { hbufA[tid] = 0.f; hbufB[tid] = 0.f; }
  float c = 0.f;  // cell state (kept redundantly in both k-half lanes)
  const float* xp = xw + (size_t)b * TT * G4 + r;
  float xi = xp[0], xf = xp[128], xg = xp[256], xo = xp[384];
  __syncthreads();
#pragma unroll 1
  for (int t = 0; t < TT; ++t) {
    xp += G4;
    float ni = xp[0], nf = xp[128], ng = xp[256], no = xp[384];  // prefetch t+1
    const f4* hr = (const f4*)((t & 1) ? hbufB : hbufA) + ks * 16;
    float* hw = (t & 1) ? hbufA : hbufB;
    f2 a0 = {0.f, 0.f}, a1 = {0.f, 0.f}, a2 = {0.f, 0.f}, a3 = {0.f, 0.f};
#pragma unroll
    for (int q = 0; q < 16; ++q) {
      f4 h4 = hr[q];
      f2 hlo = {h4.x, h4.y}, hhi = {h4.z, h4.w};
      a0 = __builtin_elementwise_fma(hlo, w0[2 * q], a0);
      a1 = __builtin_elementwise_fma(hlo, w1[2 * q], a1);
      a2 = __builtin_elementwise_fma(hlo, w2[2 * q], a2);
      a3 = __builtin_elementwise_fma(hlo, w3[2 * q], a3);
      a0 = __builtin_elementwise_fma(hhi, w0[2 * q + 1], a0);
      a1 = __builtin_elementwise_fma(hhi, w1[2 * q + 1], a1);
      a2 = __builtin_elementwise_fma(hhi, w2[2 * q + 1], a2);
      a3 = __builtin_elementwise_fma(hhi, w3[2 * q + 1], a3);
    }
    float si = a0.x + a0.y, sf = a1.x + a1.y, sg = a2.x + a2.y, so = a3.x + a3.y;
    si += __shfl_xor(si, 1, 64);  // combine k-halves (same-wave lane pair)
    sf += __shfl_xor(sf, 1, 64);
    sg += __shfl_xor(sg, 1, 64);
    so += __shfl_xor(so, 1, 64);
    si += xi; sf += xf; sg += xg; so += xo;
    float ig = sigm(si), fg = sigm(sf), gg = tanh_fast(sg), og = sigm(so);
    c = fmaf(fg, c, ig * gg);
    float hv = og * tanh_fast(c);
    if (ks == 0) hw[r] = hv;
    LDS_BARRIER();
    xi = ni; xf = nf; xg = ng; xo = no;
  }
  // after t=511 the final h is in hbufA ((511&1)=1 -> wrote hbufA)
  if (tid < 4) {
    float acc = b_fc[tid];
#pragma unroll 8
    for (int k = 0; k < HH; ++k) acc = fmaf(hbufA[k], W_fc[k * 4 + tid], acc);
    out[b * 4 + tid] = acc;
  }
}

extern "C" void kernel_launch(void* const* d_in, const int* in_sizes, int n_in,
                              void* d_out, int out_size, void* d_ws, size_t ws_size,
                              hipStream_t stream) {
  const float* x_seq   = (const float*)d_in[0];
  const int*   ei      = (const int*)d_in[1];
  const float* w_gat   = (const float*)d_in[2];
  const float* att_src = (const float*)d_in[3];
  const float* att_dst = (const float*)d_in[4];
  const float* b_gat   = (const float*)d_in[5];
  const float* W_ih    = (const float*)d_in[6];
  const float* W_hh    = (const float*)d_in[7];
  const float* b_ih    = (const float*)d_in[8];
  const float* b_hh    = (const float*)d_in[9];
  const float* W_fc    = (const float*)d_in[10];
  const float* b_fc    = (const float*)d_in[11];

  float* ws = (float*)d_ws;
  float* xw       = ws;                               // (16384+1)*512 floats (1 pad row for prefetch)
  float* W_eff    = xw + (size_t)(NPOS + 1) * G4;     // 32*512
  float* bias_eff = W_eff + NN * G4;                  // 512
  float* scal     = bias_eff + G4;                    // 2
  float* biasp    = scal + 2;                         // 32*512
  int*   srt_g    = (int*)(biasp + NN * G4);          // 128
  int*   off_g    = srt_g + ET;                       // 33

  prep_kernel<<<NN, G4, 0, stream>>>(w_gat, b_gat, W_ih, W_eff, biasp);
  prep2_kernel<<<1, G4, 0, stream>>>(biasp, b_ih, b_hh, w_gat, att_src, att_dst, ei,
                                     bias_eff, scal, srt_g, off_g);
  gatxw_kernel<<<NPOS / 8, 256, 0, stream>>>(x_seq, srt_g, off_g, scal, W_eff, bias_eff, xw);
  lstm_kernel<<<BB, 256, 0, stream>>>(xw, W_hh, W_fc, b_fc, (float*)d_out);
}

// Round 6
// 473.821 us; speedup vs baseline: 1.4487x; 1.4487x over previous
//
#include <hip/hip_runtime.h>

#define NN 32      // nodes
#define FF 64      // GAT out features
#define HH 128     // LSTM hidden
#define G4 512     // 4*H
#define BB 32      // batch
#define TT 512     // time steps
#define ET 128     // 96 edges + 32 self loops
#define NPOS (BB*TT)

typedef float f2 __attribute__((ext_vector_type(2)));
typedef float f4 __attribute__((ext_vector_type(4)));

__device__ __forceinline__ float frcp(float x) { return __builtin_amdgcn_rcpf(x); }
__device__ __forceinline__ float sigm(float x) { return frcp(1.f + __expf(-x)); }
__device__ __forceinline__ float tanh_fast(float x) { return 1.f - 2.f * frcp(1.f + __expf(2.f * x)); }

// raw barrier: LDS drain only — does NOT drain vmcnt, so global prefetches
// issued before it stay in flight (unlike __syncthreads, which drains vmcnt(0))
#define LDS_BARRIER() asm volatile("s_waitcnt lgkmcnt(0)\n\ts_barrier" ::: "memory")

// ---------------- prep: fold GAT linear into LSTM input weights ----------------
__global__ __launch_bounds__(512) void prep_kernel(const float* __restrict__ w_gat,
                                                   const float* __restrict__ b_gat,
                                                   const float* __restrict__ W_ih,
                                                   float* __restrict__ W_eff,
                                                   float* __restrict__ biasp) {
  int j = threadIdx.x;
  int n = blockIdx.x;
  float accw = 0.f, accb = 0.f;
#pragma unroll 8
  for (int f = 0; f < FF; ++f) {
    float wv = W_ih[(n * FF + f) * G4 + j];
    accw = fmaf(w_gat[f], wv, accw);
    accb = fmaf(b_gat[f], wv, accb);
  }
  W_eff[n * G4 + j] = accw;
  biasp[n * G4 + j] = accb;
}

// bias reduce + attention scalars + edge count-sort by dst
__global__ __launch_bounds__(512) void prep2_kernel(const float* __restrict__ biasp,
                                                    const float* __restrict__ b_ih,
                                                    const float* __restrict__ b_hh,
                                                    const float* __restrict__ w_gat,
                                                    const float* __restrict__ att_src,
                                                    const float* __restrict__ att_dst,
                                                    const int* __restrict__ ei,
                                                    float* __restrict__ bias_eff,
                                                    float* __restrict__ scal,
                                                    int* __restrict__ srt_g,
                                                    int* __restrict__ off_g) {
  __shared__ int cnt[NN];
  __shared__ int off[NN + 1];
  __shared__ int srt[ET];
  int j = threadIdx.x;
  if (j < NN) cnt[j] = 0;
  float acc = b_ih[j] + b_hh[j];
#pragma unroll
  for (int n = 0; n < NN; ++n) acc += biasp[n * G4 + j];
  bias_eff[j] = acc;
  if (j == 0) {
    float cs = 0.f, cd = 0.f;
    for (int f = 0; f < FF; ++f) {
      cs = fmaf(w_gat[f], att_src[f], cs);
      cd = fmaf(w_gat[f], att_dst[f], cd);
    }
    scal[0] = cs;
    scal[1] = cd;
  }
  __syncthreads();
  int s = 0, d = 0, tk = 0;
  if (j < ET) {
    if (j < 96) { s = ei[j]; d = ei[96 + j]; }
    else { s = j - 96; d = j - 96; }
    tk = atomicAdd(&cnt[d], 1);
  }
  __syncthreads();
  if (j == 0) {
    off[0] = 0;
    for (int n = 0; n < NN; ++n) off[n + 1] = off[n] + cnt[n];
  }
  __syncthreads();
  if (j < ET) srt[off[d] + tk] = s;
  __syncthreads();
  if (j < ET) srt_g[j] = srt[j];
  if (j < NN + 1) off_g[j] = off[j];
}

// ---------------- fused GAT + xw: 8 positions per 256-thread block ----------------
__global__ __launch_bounds__(256) void gatxw_kernel(const float* __restrict__ x_seq,
                                                    const int* __restrict__ srt_g,
                                                    const int* __restrict__ off_g,
                                                    const float* __restrict__ scal,
                                                    const float* __restrict__ W_eff,
                                                    const float* __restrict__ bias_eff,
                                                    float* __restrict__ xw) {
  __shared__ int srt[ET];
  __shared__ int offs[NN + 1];
  __shared__ float xs[8 * 32];
  __shared__ float sl[8 * 32];
  int tid = threadIdx.x;
  int posbase = blockIdx.x * 8;
  float we0[NN], we1[NN];
#pragma unroll
  for (int nn = 0; nn < NN; ++nn) {
    we0[nn] = W_eff[nn * G4 + tid];
    we1[nn] = W_eff[nn * G4 + 256 + tid];
  }
  float b0 = bias_eff[tid], b1 = bias_eff[256 + tid];
  if (tid < ET) srt[tid] = srt_g[tid];
  if (tid < NN + 1) offs[tid] = off_g[tid];
  int p = tid >> 5, n = tid & 31;
  xs[tid] = x_seq[posbase * NN + tid];  // coalesced
  __syncthreads();
  float cs = scal[0], cd = scal[1];
  int base = p * 32;
  int e0 = offs[n], e1 = offs[n + 1];
  float xn = xs[base + n];
  float cdxn = cd * xn;
  float m = -3.0e38f;
  for (int e = e0; e < e1; ++e) {
    float ev = fmaf(cs, xs[base + srt[e]], cdxn);
    ev = ev > 0.f ? ev : 0.2f * ev;  // LeakyReLU(0.2)
    m = fmaxf(m, ev);
  }
  float z = 0.f, sa = 0.f;
  for (int e = e0; e < e1; ++e) {
    float xsv = xs[base + srt[e]];
    float ev = fmaf(cs, xsv, cdxn);
    ev = ev > 0.f ? ev : 0.2f * ev;
    float ex = __expf(ev - m);
    z += ex;
    sa = fmaf(ex, xsv, sa);
  }
  sl[p * 32 + n] = sa * frcp(z);
  __syncthreads();
  for (int pp = 0; pp < 8; ++pp) {
    const float4* sp = (const float4*)&sl[pp * 32];
    float a0 = b0, a1 = b1;
#pragma unroll
    for (int q = 0; q < 8; ++q) {
      float4 sv = sp[q];
      a0 = fmaf(sv.x, we0[4 * q], a0);
      a0 = fmaf(sv.y, we0[4 * q + 1], a0);
      a0 = fmaf(sv.z, we0[4 * q + 2], a0);
      a0 = fmaf(sv.w, we0[4 * q + 3], a0);
      a1 = fmaf(sv.x, we1[4 * q], a1);
      a1 = fmaf(sv.y, we1[4 * q + 1], a1);
      a1 = fmaf(sv.z, we1[4 * q + 2], a1);
      a1 = fmaf(sv.w, we1[4 * q + 3], a1);
    }
    size_t row = (size_t)(posbase + pp) * G4;
    xw[row + tid] = a0;
    xw[row + 256 + tid] = a1;
  }
}

// ---------------- LSTM scan ----------------
// 512 thr/block; thread (r,kq): r=row 0..127 (tid>>2), kq=k-quarter (tid&3).
// Owns gate cols {r, 128+r, 256+r, 384+r} restricted to k in [kq*32,kq*32+32):
//  - weights: 128 floats = 32 named f4 (X-macro; in-loop asm "+v" pin each iter
//    makes remat AND AGPR-parking unprofitable; bounds(512,2) => 256-reg cap)
//  - h in LDS partitioned: quarter kq at float-offset kq*40 (8-bank stagger)
//    => per-instr the 4 quad addresses hit disjoint banks; 128 B/thread/step
//    => 64 KB/step LDS return (vs 256 KB in R1/R3/R4)
//  - quad reduce: 2x shfl_xor (same wave); activations redundant in the quad;
//    c redundant per lane; kq==0 lane writes h
//  - double-buffered h, ONE lgkm-only barrier/step; x prefetch stays in flight
#define FOR_GQ(X) \
  X(0,0) X(0,1) X(0,2) X(0,3) X(0,4) X(0,5) X(0,6) X(0,7) \
  X(1,0) X(1,1) X(1,2) X(1,3) X(1,4) X(1,5) X(1,6) X(1,7) \
  X(2,0) X(2,1) X(2,2) X(2,3) X(2,4) X(2,5) X(2,6) X(2,7) \
  X(3,0) X(3,1) X(3,2) X(3,3) X(3,4) X(3,5) X(3,6) X(3,7)

#define DECLW(g, q) f4 w_##g##_##q = { wcol[(4*q+0)*G4 + g*128], wcol[(4*q+1)*G4 + g*128], \
                                       wcol[(4*q+2)*G4 + g*128], wcol[(4*q+3)*G4 + g*128] };
#define FMAW(g, q) acc##g = __builtin_elementwise_fma(hv##q, w_##g##_##q, acc##g);

__global__ __launch_bounds__(512, 2) void lstm_kernel(const float* __restrict__ xw,
                                                      const float* __restrict__ W_hh,
                                                      const float* __restrict__ W_fc,
                                                      const float* __restrict__ b_fc,
                                                      float* __restrict__ out) {
  __shared__ float hrep[2][4 * 40];  // [buf][quarter kq at kq*40 + (k&31)]
  int b = blockIdx.x, tid = threadIdx.x;
  int r = tid >> 2, kq = tid & 3;
  const float* wcol = W_hh + (size_t)(kq * 32) * G4 + r;
  FOR_GQ(DECLW)  // 32 named f4 = 128 weight floats
  if (tid < 160) { hrep[0][tid % 160] = 0.f; hrep[1][tid % 160] = 0.f; }
  float c = 0.f;  // cell state (redundant across the quad)
  const float* xp = xw + (size_t)b * TT * G4 + kq * 128 + r;
  float xv = *xp;  // x for t=0 (this lane's gate = kq)
  __syncthreads();
#pragma unroll 1
  for (int t = 0; t < TT; ++t) {
    // pin weights in arch VGPRs at every iteration boundary
    asm volatile("" : "+v"(w_0_0), "+v"(w_0_1), "+v"(w_0_2), "+v"(w_0_3),
                      "+v"(w_0_4), "+v"(w_0_5), "+v"(w_0_6), "+v"(w_0_7),
                      "+v"(w_1_0), "+v"(w_1_1), "+v"(w_1_2), "+v"(w_1_3),
                      "+v"(w_1_4), "+v"(w_1_5), "+v"(w_1_6), "+v"(w_1_7));
    asm volatile("" : "+v"(w_2_0), "+v"(w_2_1), "+v"(w_2_2), "+v"(w_2_3),
                      "+v"(w_2_4), "+v"(w_2_5), "+v"(w_2_6), "+v"(w_2_7),
                      "+v"(w_3_0), "+v"(w_3_1), "+v"(w_3_2), "+v"(w_3_3),
                      "+v"(w_3_4), "+v"(w_3_5), "+v"(w_3_6), "+v"(w_3_7));
    xp += G4;
    float xn = *xp;  // prefetch t+1; survives lgkm-only barrier
    const f4* hb = (const f4*)&hrep[t & 1][kq * 40];
    f4 hv0 = hb[0], hv1 = hb[1], hv2 = hb[2], hv3 = hb[3];
    f4 hv4 = hb[4], hv5 = hb[5], hv6 = hb[6], hv7 = hb[7];
    f4 acc0 = {0.f, 0.f, 0.f, 0.f}, acc1 = acc0, acc2 = acc0, acc3 = acc0;
    FOR_GQ(FMAW)  // 64 v_pk_fma_f32
    float s0 = (acc0.x + acc0.y) + (acc0.z + acc0.w);
    float s1 = (acc1.x + acc1.y) + (acc1.z + acc1.w);
    float s2 = (acc2.x + acc2.y) + (acc2.z + acc2.w);
    float s3 = (acc3.x + acc3.y) + (acc3.z + acc3.w);
    // fold this lane's x (gate kq) in before the butterfly
    s0 += (kq == 0) ? xv : 0.f;
    s1 += (kq == 1) ? xv : 0.f;
    s2 += (kq == 2) ? xv : 0.f;
    s3 += (kq == 3) ? xv : 0.f;
    s0 += __shfl_xor(s0, 1, 64); s0 += __shfl_xor(s0, 2, 64);
    s1 += __shfl_xor(s1, 1, 64); s1 += __shfl_xor(s1, 2, 64);
    s2 += __shfl_xor(s2, 1, 64); s2 += __shfl_xor(s2, 2, 64);
    s3 += __shfl_xor(s3, 1, 64); s3 += __shfl_xor(s3, 2, 64);
    float ig = sigm(s0), fg = sigm(s1), gg = tanh_fast(s2), og = sigm(s3);
    c = fmaf(fg, c, ig * gg);
    float hvnew = og * tanh_fast(c);
    if (kq == 0) hrep[(t + 1) & 1][(r >> 5) * 40 + (r & 31)] = hvnew;
    LDS_BARRIER();
    xv = xn;
  }
  // final h (t=512) sits in buf 0; classifier
  if (tid < 4) {
    float acc = b_fc[tid];
#pragma unroll 8
    for (int k = 0; k < HH; ++k)
      acc = fmaf(hrep[0][(k >> 5) * 40 + (k & 31)], W_fc[k * 4 + tid], acc);
    out[b * 4 + tid] = acc;
  }
}

extern "C" void kernel_launch(void* const* d_in, const int* in_sizes, int n_in,
                              void* d_out, int out_size, void* d_ws, size_t ws_size,
                              hipStream_t stream) {
  const float* x_seq   = (const float*)d_in[0];
  const int*   ei      = (const int*)d_in[1];
  const float* w_gat   = (const float*)d_in[2];
  const float* att_src = (const float*)d_in[3];
  const float* att_dst = (const float*)d_in[4];
  const float* b_gat   = (const float*)d_in[5];
  const float* W_ih    = (const float*)d_in[6];
  const float* W_hh    = (const float*)d_in[7];
  const float* b_ih    = (const float*)d_in[8];
  const float* b_hh    = (const float*)d_in[9];
  const float* W_fc    = (const float*)d_in[10];
  const float* b_fc    = (const float*)d_in[11];

  float* ws = (float*)d_ws;
  float* xw       = ws;                               // (16384+1)*512 floats (pad row for prefetch)
  float* W_eff    = xw + (size_t)(NPOS + 1) * G4;     // 32*512
  float* bias_eff = W_eff + NN * G4;                  // 512
  float* scal     = bias_eff + G4;                    // 2
  float* biasp    = scal + 2;                         // 32*512
  int*   srt_g    = (int*)(biasp + NN * G4);          // 128
  int*   off_g    = srt_g + ET;                       // 33

  prep_kernel<<<NN, G4, 0, stream>>>(w_gat, b_gat, W_ih, W_eff, biasp);
  prep2_kernel<<<1, G4, 0, stream>>>(biasp, b_ih, b_hh, w_gat, att_src, att_dst, ei,
                                     bias_eff, scal, srt_g, off_g);
  gatxw_kernel<<<NPOS / 8, 256, 0, stream>>>(x_seq, srt_g, off_g, scal, W_eff, bias_eff, xw);
  lstm_kernel<<<BB, G4, 0, stream>>>(xw, W_hh, W_fc, b_fc, (float*)d_out);
}

// Round 7
// 410.253 us; speedup vs baseline: 1.6732x; 1.1549x over previous
//
#include <hip/hip_runtime.h>

#define NN 32      // nodes
#define FF 64      // GAT out features
#define HH 128     // LSTM hidden
#define G4 512     // 4*H
#define BB 32      // batch
#define TT 512     // time steps
#define ET 128     // 96 edges + 32 self loops
#define NPOS (BB*TT)

__device__ __forceinline__ float frcp(float x) { return __builtin_amdgcn_rcpf(x); }

// ---------------- prep: fold GAT linear into LSTM input weights ----------------
__global__ __launch_bounds__(512) void prep_kernel(const float* __restrict__ w_gat,
                                                   const float* __restrict__ b_gat,
                                                   const float* __restrict__ W_ih,
                                                   float* __restrict__ W_eff,
                                                   float* __restrict__ biasp) {
  int j = threadIdx.x;
  int n = blockIdx.x;
  float accw = 0.f, accb = 0.f;
#pragma unroll 8
  for (int f = 0; f < FF; ++f) {
    float wv = W_ih[(n * FF + f) * G4 + j];
    accw = fmaf(w_gat[f], wv, accw);
    accb = fmaf(b_gat[f], wv, accb);
  }
  W_eff[n * G4 + j] = accw;
  biasp[n * G4 + j] = accb;
}

// bias reduce + attention scalars + edge count-sort by dst
__global__ __launch_bounds__(512) void prep2_kernel(const float* __restrict__ biasp,
                                                    const float* __restrict__ b_ih,
                                                    const float* __restrict__ b_hh,
                                                    const float* __restrict__ w_gat,
                                                    const float* __restrict__ att_src,
                                                    const float* __restrict__ att_dst,
                                                    const int* __restrict__ ei,
                                                    float* __restrict__ bias_eff,
                                                    float* __restrict__ scal,
                                                    int* __restrict__ srt_g,
                                                    int* __restrict__ off_g) {
  __shared__ int cnt[NN];
  __shared__ int off[NN + 1];
  __shared__ int srt[ET];
  int j = threadIdx.x;
  if (j < NN) cnt[j] = 0;
  float acc = b_ih[j] + b_hh[j];
#pragma unroll
  for (int n = 0; n < NN; ++n) acc += biasp[n * G4 + j];
  bias_eff[j] = acc;
  if (j == 0) {
    float cs = 0.f, cd = 0.f;
    for (int f = 0; f < FF; ++f) {
      cs = fmaf(w_gat[f], att_src[f], cs);
      cd = fmaf(w_gat[f], att_dst[f], cd);
    }
    scal[0] = cs;
    scal[1] = cd;
  }
  __syncthreads();
  int s = 0, d = 0, tk = 0;
  if (j < ET) {
    if (j < 96) { s = ei[j]; d = ei[96 + j]; }
    else { s = j - 96; d = j - 96; }
    tk = atomicAdd(&cnt[d], 1);
  }
  __syncthreads();
  if (j == 0) {
    off[0] = 0;
    for (int n = 0; n < NN; ++n) off[n + 1] = off[n] + cnt[n];
  }
  __syncthreads();
  if (j < ET) srt[off[d] + tk] = s;
  __syncthreads();
  if (j < ET) srt_g[j] = srt[j];
  if (j < NN + 1) off_g[j] = off[j];
}

// ---------------- prep3: per-thread weight transpose for the asm LSTM ----------------
// Wt[tid*128 + g*32 + kk] = W_hh[(kq*32+kk)][g*128 + r],  tid = r*4+kq
__global__ __launch_bounds__(128) void prep3_kernel(const float* __restrict__ W_hh,
                                                    float* __restrict__ Wt) {
  int tid = blockIdx.x;   // 0..511
  int m = threadIdx.x;    // 0..127
  int r = tid >> 2, kq = tid & 3;
  int g = m >> 5, kk = m & 31;
  Wt[tid * 128 + m] = W_hh[(kq * 32 + kk) * G4 + g * 128 + r];
}

// ---------------- fused GAT + xw: 8 positions per 256-thread block ----------------
__global__ __launch_bounds__(256) void gatxw_kernel(const float* __restrict__ x_seq,
                                                    const int* __restrict__ srt_g,
                                                    const int* __restrict__ off_g,
                                                    const float* __restrict__ scal,
                                                    const float* __restrict__ W_eff,
                                                    const float* __restrict__ bias_eff,
                                                    float* __restrict__ xw) {
  __shared__ int srt[ET];
  __shared__ int offs[NN + 1];
  __shared__ float xs[8 * 32];
  __shared__ float sl[8 * 32];
  int tid = threadIdx.x;
  int posbase = blockIdx.x * 8;
  float we0[NN], we1[NN];
#pragma unroll
  for (int nn = 0; nn < NN; ++nn) {
    we0[nn] = W_eff[nn * G4 + tid];
    we1[nn] = W_eff[nn * G4 + 256 + tid];
  }
  float b0 = bias_eff[tid], b1 = bias_eff[256 + tid];
  if (tid < ET) srt[tid] = srt_g[tid];
  if (tid < NN + 1) offs[tid] = off_g[tid];
  int p = tid >> 5, n = tid & 31;
  xs[tid] = x_seq[posbase * NN + tid];  // coalesced
  __syncthreads();
  float cs = scal[0], cd = scal[1];
  int base = p * 32;
  int e0 = offs[n], e1 = offs[n + 1];
  float xn = xs[base + n];
  float cdxn = cd * xn;
  float m = -3.0e38f;
  for (int e = e0; e < e1; ++e) {
    float ev = fmaf(cs, xs[base + srt[e]], cdxn);
    ev = ev > 0.f ? ev : 0.2f * ev;  // LeakyReLU(0.2)
    m = fmaxf(m, ev);
  }
  float z = 0.f, sa = 0.f;
  for (int e = e0; e < e1; ++e) {
    float xsv = xs[base + srt[e]];
    float ev = fmaf(cs, xsv, cdxn);
    ev = ev > 0.f ? ev : 0.2f * ev;
    float ex = __expf(ev - m);
    z += ex;
    sa = fmaf(ex, xsv, sa);
  }
  sl[p * 32 + n] = sa * frcp(z);
  __syncthreads();
  for (int pp = 0; pp < 8; ++pp) {
    const float4* sp = (const float4*)&sl[pp * 32];
    float a0 = b0, a1 = b1;
#pragma unroll
    for (int q = 0; q < 8; ++q) {
      float4 sv = sp[q];
      a0 = fmaf(sv.x, we0[4 * q], a0);
      a0 = fmaf(sv.y, we0[4 * q + 1], a0);
      a0 = fmaf(sv.z, we0[4 * q + 2], a0);
      a0 = fmaf(sv.w, we0[4 * q + 3], a0);
      a1 = fmaf(sv.x, we1[4 * q], a1);
      a1 = fmaf(sv.y, we1[4 * q + 1], a1);
      a1 = fmaf(sv.z, we1[4 * q + 2], a1);
      a1 = fmaf(sv.w, we1[4 * q + 3], a1);
    }
    size_t row = (size_t)(posbase + pp) * G4;
    xw[row + tid] = a0;
    xw[row + 256 + tid] = a1;
  }
}

// ---------------- LSTM scan: whole t-loop in inline asm ----------------
// Thread (r,kq), tid=r*4+kq: 4 gate cols {g*128+r}, k in [kq*32,kq*32+32).
// Explicit regs: v[64:191] weights (loaded once, in-asm), v[32:63] h quads,
// v[192:223] state/temps. Clobbers force VGPR alloc ~224 -> weights STAY
// register-resident (R1-R6: compiler spilled at every source-level attempt).
// h layout: quarter kq at byte offset kq*160 (8-bank stagger, 0 conflicts, R6).
// Quad reduce via DPP quad_perm adds. x prefetched with vmcnt(1), lgkm-only
// barrier. Unroll x2 for h buffer A/B ping-pong (bufB at +640 B).

#define PK16(HP, W0, W1, W2, W3, SRC2A, SRC2B, SRC2C, SRC2D) \
  "v_pk_fma_f32 v[216:217], v[" HP "], v[" W0 "], " SRC2A "\n\t" \
  "v_pk_fma_f32 v[218:219], v[" HP "], v[" W1 "], " SRC2B "\n\t" \
  "v_pk_fma_f32 v[220:221], v[" HP "], v[" W2 "], " SRC2C "\n\t" \
  "v_pk_fma_f32 v[222:223], v[" HP "], v[" W3 "], " SRC2D "\n\t"

#define PK_BLOCK \
  PK16("32:33", "64:65",  "96:97",   "128:129", "160:161", "0", "0", "0", "0") \
  PK16("34:35", "66:67",  "98:99",   "130:131", "162:163", "v[216:217]", "v[218:219]", "v[220:221]", "v[222:223]") \
  PK16("36:37", "68:69",  "100:101", "132:133", "164:165", "v[216:217]", "v[218:219]", "v[220:221]", "v[222:223]") \
  PK16("38:39", "70:71",  "102:103", "134:135", "166:167", "v[216:217]", "v[218:219]", "v[220:221]", "v[222:223]") \
  PK16("40:41", "72:73",  "104:105", "136:137", "168:169", "v[216:217]", "v[218:219]", "v[220:221]", "v[222:223]") \
  PK16("42:43", "74:75",  "106:107", "138:139", "170:171", "v[216:217]", "v[218:219]", "v[220:221]", "v[222:223]") \
  PK16("44:45", "76:77",  "108:109", "140:141", "172:173", "v[216:217]", "v[218:219]", "v[220:221]", "v[222:223]") \
  PK16("46:47", "78:79",  "110:111", "142:143", "174:175", "v[216:217]", "v[218:219]", "v[220:221]", "v[222:223]") \
  PK16("48:49", "80:81",  "112:113", "144:145", "176:177", "v[216:217]", "v[218:219]", "v[220:221]", "v[222:223]") \
  PK16("50:51", "82:83",  "114:115", "146:147", "178:179", "v[216:217]", "v[218:219]", "v[220:221]", "v[222:223]") \
  PK16("52:53", "84:85",  "116:117", "148:149", "180:181", "v[216:217]", "v[218:219]", "v[220:221]", "v[222:223]") \
  PK16("54:55", "86:87",  "118:119", "150:151", "182:183", "v[216:217]", "v[218:219]", "v[220:221]", "v[222:223]") \
  PK16("56:57", "88:89",  "120:121", "152:153", "184:185", "v[216:217]", "v[218:219]", "v[220:221]", "v[222:223]") \
  PK16("58:59", "90:91",  "122:123", "154:155", "186:187", "v[216:217]", "v[218:219]", "v[220:221]", "v[222:223]") \
  PK16("60:61", "92:93",  "124:125", "156:157", "188:189", "v[216:217]", "v[218:219]", "v[220:221]", "v[222:223]") \
  PK16("62:63", "94:95",  "126:127", "158:159", "190:191", "v[216:217]", "v[218:219]", "v[220:221]", "v[222:223]")

#define PHASE(XLOAD, XUSE, RD, WR) \
  "global_load_dword " XLOAD ", v194, %[xwb]\n\t" \
  "v_add_u32 v194, 0x800, v194\n\t" \
  "ds_read_b128 v[32:35], " RD "\n\t" \
  "ds_read_b128 v[36:39], " RD " offset:16\n\t" \
  "ds_read_b128 v[40:43], " RD " offset:32\n\t" \
  "ds_read_b128 v[44:47], " RD " offset:48\n\t" \
  "ds_read_b128 v[48:51], " RD " offset:64\n\t" \
  "ds_read_b128 v[52:55], " RD " offset:80\n\t" \
  "ds_read_b128 v[56:59], " RD " offset:96\n\t" \
  "ds_read_b128 v[60:63], " RD " offset:112\n\t" \
  "s_waitcnt lgkmcnt(0)\n\t" \
  PK_BLOCK \
  "v_add_f32 v204, v216, v217\n\t" \
  "v_add_f32 v205, v218, v219\n\t" \
  "v_add_f32 v206, v220, v221\n\t" \
  "v_add_f32 v207, v222, v223\n\t" \
  "s_waitcnt vmcnt(1)\n\t" \
  "v_fmac_f32 v204, " XUSE ", v200\n\t" \
  "v_fmac_f32 v205, " XUSE ", v201\n\t" \
  "v_fmac_f32 v206, " XUSE ", v202\n\t" \
  "v_fmac_f32 v207, " XUSE ", v203\n\t" \
  "v_add_f32_dpp v204, v204, v204 quad_perm:[1,0,3,2] row_mask:0xf bank_mask:0xf\n\t" \
  "v_add_f32_dpp v205, v205, v205 quad_perm:[1,0,3,2] row_mask:0xf bank_mask:0xf\n\t" \
  "v_add_f32_dpp v206, v206, v206 quad_perm:[1,0,3,2] row_mask:0xf bank_mask:0xf\n\t" \
  "v_add_f32_dpp v207, v207, v207 quad_perm:[1,0,3,2] row_mask:0xf bank_mask:0xf\n\t" \
  "v_add_f32_dpp v204, v204, v204 quad_perm:[2,3,0,1] row_mask:0xf bank_mask:0xf\n\t" \
  "v_add_f32_dpp v205, v205, v205 quad_perm:[2,3,0,1] row_mask:0xf bank_mask:0xf\n\t" \
  "v_add_f32_dpp v206, v206, v206 quad_perm:[2,3,0,1] row_mask:0xf bank_mask:0xf\n\t" \
  "v_add_f32_dpp v207, v207, v207 quad_perm:[2,3,0,1] row_mask:0xf bank_mask:0xf\n\t" \
  "v_mul_f32 v208, 0xbfb8aa3b, v204\n\t" \
  "v_mul_f32 v209, 0xbfb8aa3b, v205\n\t" \
  "v_mul_f32 v210, 0x4038aa3b, v206\n\t" \
  "v_mul_f32 v211, 0xbfb8aa3b, v207\n\t" \
  "v_exp_f32 v208, v208\n\t" \
  "v_exp_f32 v209, v209\n\t" \
  "v_exp_f32 v210, v210\n\t" \
  "v_exp_f32 v211, v211\n\t" \
  "v_add_f32 v208, 1.0, v208\n\t" \
  "v_add_f32 v209, 1.0, v209\n\t" \
  "v_add_f32 v210, 1.0, v210\n\t" \
  "v_add_f32 v211, 1.0, v211\n\t" \
  "v_rcp_f32 v208, v208\n\t" \
  "v_rcp_f32 v209, v209\n\t" \
  "v_rcp_f32 v210, v210\n\t" \
  "v_rcp_f32 v211, v211\n\t" \
  "v_fma_f32 v210, -2.0, v210, 1.0\n\t" \
  "v_mul_f32 v212, v208, v210\n\t" \
  "v_fma_f32 v199, v209, v199, v212\n\t" \
  "v_mul_f32 v214, 0x4038aa3b, v199\n\t" \
  "v_exp_f32 v214, v214\n\t" \
  "s_nop 1\n\t" \
  "v_add_f32 v214, 1.0, v214\n\t" \
  "v_rcp_f32 v214, v214\n\t" \
  "s_nop 1\n\t" \
  "v_fma_f32 v214, -2.0, v214, 1.0\n\t" \
  "v_mul_f32 v213, v211, v214\n\t" \
  "ds_write_b32 " WR ", v213\n\t" \
  "s_waitcnt lgkmcnt(0)\n\t" \
  "s_barrier\n\t"

__global__ __launch_bounds__(512, 2) void lstm_kernel(const float* __restrict__ xw,
                                                      const float* __restrict__ Wt,
                                                      const float* __restrict__ W_fc,
                                                      const float* __restrict__ b_fc,
                                                      float* __restrict__ out) {
  __shared__ __align__(16) float lds[320];  // hA [0,160) floats, hB [160,320)
  int b = blockIdx.x, tid = threadIdx.x;
  int r = tid >> 2, kq = tid & 3;
  if (tid < 320) lds[tid] = 0.f;
  const float* xwb = xw + (size_t)b * TT * G4;
  float xv0 = xwb[kq * 128 + r];
  unsigned xoff0 = (unsigned)((kq * 128 + r + G4) * 4);
  unsigned wtoff = (unsigned)(tid * 512);
  unsigned lbase = (unsigned)(uintptr_t)&lds[0];  // LDS aperture is 4GB-aligned
  unsigned rda = lbase + kq * 160;
  unsigned rdb = rda + 640;
  unsigned wra = lbase + (((r >> 5) * 40 + (r & 31)) << 2);
  unsigned wrb = wra + 640;
  float mh0 = (kq == 0) ? 1.f : 0.f;
  float mh1 = (kq == 1) ? 1.f : 0.f;
  float mh2 = (kq == 2) ? 1.f : 0.f;
  float mh3 = (kq == 3) ? 1.f : 0.f;
  __syncthreads();
  asm volatile(
    "v_mov_b32 v194, %[xo]\n\t"
    "v_mov_b32 v193, %[xv0]\n\t"
    "v_mov_b32 v195, %[rda]\n\t"
    "v_mov_b32 v196, %[rdb]\n\t"
    "v_mov_b32 v197, %[wra]\n\t"
    "v_mov_b32 v198, %[wrb]\n\t"
    "v_mov_b32 v199, 0\n\t"
    "v_mov_b32 v200, %[m0]\n\t"
    "v_mov_b32 v201, %[m1]\n\t"
    "v_mov_b32 v202, %[m2]\n\t"
    "v_mov_b32 v203, %[m3]\n\t"
    "global_load_dwordx4 v[64:67], %[wto], %[wtb] offset:0\n\t"
    "global_load_dwordx4 v[68:71], %[wto], %[wtb] offset:16\n\t"
    "global_load_dwordx4 v[72:75], %[wto], %[wtb] offset:32\n\t"
    "global_load_dwordx4 v[76:79], %[wto], %[wtb] offset:48\n\t"
    "global_load_dwordx4 v[80:83], %[wto], %[wtb] offset:64\n\t"
    "global_load_dwordx4 v[84:87], %[wto], %[wtb] offset:80\n\t"
    "global_load_dwordx4 v[88:91], %[wto], %[wtb] offset:96\n\t"
    "global_load_dwordx4 v[92:95], %[wto], %[wtb] offset:112\n\t"
    "global_load_dwordx4 v[96:99], %[wto], %[wtb] offset:128\n\t"
    "global_load_dwordx4 v[100:103], %[wto], %[wtb] offset:144\n\t"
    "global_load_dwordx4 v[104:107], %[wto], %[wtb] offset:160\n\t"
    "global_load_dwordx4 v[108:111], %[wto], %[wtb] offset:176\n\t"
    "global_load_dwordx4 v[112:115], %[wto], %[wtb] offset:192\n\t"
    "global_load_dwordx4 v[116:119], %[wto], %[wtb] offset:208\n\t"
    "global_load_dwordx4 v[120:123], %[wto], %[wtb] offset:224\n\t"
    "global_load_dwordx4 v[124:127], %[wto], %[wtb] offset:240\n\t"
    "global_load_dwordx4 v[128:131], %[wto], %[wtb] offset:256\n\t"
    "global_load_dwordx4 v[132:135], %[wto], %[wtb] offset:272\n\t"
    "global_load_dwordx4 v[136:139], %[wto], %[wtb] offset:288\n\t"
    "global_load_dwordx4 v[140:143], %[wto], %[wtb] offset:304\n\t"
    "global_load_dwordx4 v[144:147], %[wto], %[wtb] offset:320\n\t"
    "global_load_dwordx4 v[148:151], %[wto], %[wtb] offset:336\n\t"
    "global_load_dwordx4 v[152:155], %[wto], %[wtb] offset:352\n\t"
    "global_load_dwordx4 v[156:159], %[wto], %[wtb] offset:368\n\t"
    "global_load_dwordx4 v[160:163], %[wto], %[wtb] offset:384\n\t"
    "global_load_dwordx4 v[164:167], %[wto], %[wtb] offset:400\n\t"
    "global_load_dwordx4 v[168:171], %[wto], %[wtb] offset:416\n\t"
    "global_load_dwordx4 v[172:175], %[wto], %[wtb] offset:432\n\t"
    "global_load_dwordx4 v[176:179], %[wto], %[wtb] offset:448\n\t"
    "global_load_dwordx4 v[180:183], %[wto], %[wtb] offset:464\n\t"
    "global_load_dwordx4 v[184:187], %[wto], %[wtb] offset:480\n\t"
    "global_load_dwordx4 v[188:191], %[wto], %[wtb] offset:496\n\t"
    "s_waitcnt vmcnt(0)\n\t"
    "s_movk_i32 s20, 0x100\n\t"
    "L_lstm_%=:\n\t"
    PHASE("v192", "v193", "v195", "v198")   // even t: read A, write B
    PHASE("v193", "v192", "v196", "v197")   // odd t:  read B, write A
    "s_sub_u32 s20, s20, 1\n\t"
    "s_cmp_lg_u32 s20, 0\n\t"
    "s_cbranch_scc1 L_lstm_%=\n\t"
    "s_waitcnt vmcnt(0) lgkmcnt(0)\n\t"
    :
    : [xwb]"s"(xwb), [wtb]"s"(Wt), [wto]"v"(wtoff), [xo]"v"(xoff0), [xv0]"v"(xv0),
      [rda]"v"(rda), [rdb]"v"(rdb), [wra]"v"(wra), [wrb]"v"(wrb),
      [m0]"v"(mh0), [m1]"v"(mh1), [m2]"v"(mh2), [m3]"v"(mh3)
    : "memory", "scc", "s20",
      "v32","v33","v34","v35","v36","v37","v38","v39",
      "v40","v41","v42","v43","v44","v45","v46","v47",
      "v48","v49","v50","v51","v52","v53","v54","v55",
      "v56","v57","v58","v59","v60","v61","v62","v63",
      "v64","v65","v66","v67","v68","v69","v70","v71",
      "v72","v73","v74","v75","v76","v77","v78","v79",
      "v80","v81","v82","v83","v84","v85","v86","v87",
      "v88","v89","v90","v91","v92","v93","v94","v95",
      "v96","v97","v98","v99","v100","v101","v102","v103",
      "v104","v105","v106","v107","v108","v109","v110","v111",
      "v112","v113","v114","v115","v116","v117","v118","v119",
      "v120","v121","v122","v123","v124","v125","v126","v127",
      "v128","v129","v130","v131","v132","v133","v134","v135",
      "v136","v137","v138","v139","v140","v141","v142","v143",
      "v144","v145","v146","v147","v148","v149","v150","v151",
      "v152","v153","v154","v155","v156","v157","v158","v159",
      "v160","v161","v162","v163","v164","v165","v166","v167",
      "v168","v169","v170","v171","v172","v173","v174","v175",
      "v176","v177","v178","v179","v180","v181","v182","v183",
      "v184","v185","v186","v187","v188","v189","v190","v191",
      "v192","v193","v194","v195","v196","v197","v198","v199",
      "v200","v201","v202","v203","v204","v205","v206","v207",
      "v208","v209","v210","v211","v212","v213","v214","v215",
      "v216","v217","v218","v219","v220","v221","v222","v223");
  __syncthreads();
  // final h (after t=511, odd) is in buffer A: lds[(k>>5)*40 + (k&31)]
  if (tid < 4) {
    float acc = b_fc[tid];
#pragma unroll 8
    for (int k = 0; k < HH; ++k)
      acc = fmaf(lds[(k >> 5) * 40 + (k & 31)], W_fc[k * 4 + tid], acc);
    out[b * 4 + tid] = acc;
  }
}

extern "C" void kernel_launch(void* const* d_in, const int* in_sizes, int n_in,
                              void* d_out, int out_size, void* d_ws, size_t ws_size,
                              hipStream_t stream) {
  const float* x_seq   = (const float*)d_in[0];
  const int*   ei      = (const int*)d_in[1];
  const float* w_gat   = (const float*)d_in[2];
  const float* att_src = (const float*)d_in[3];
  const float* att_dst = (const float*)d_in[4];
  const float* b_gat   = (const float*)d_in[5];
  const float* W_ih    = (const float*)d_in[6];
  const float* W_hh    = (const float*)d_in[7];
  const float* b_ih    = (const float*)d_in[8];
  const float* b_hh    = (const float*)d_in[9];
  const float* W_fc    = (const float*)d_in[10];
  const float* b_fc    = (const float*)d_in[11];

  float* ws = (float*)d_ws;
  float* Wt       = ws;                               // 512*128 = 65536 f (16B-aligned)
  float* xw       = Wt + 65536;                       // (16384+1)*512 f (pad row for prefetch)
  float* W_eff    = xw + (size_t)(NPOS + 1) * G4;     // 32*512
  float* bias_eff = W_eff + NN * G4;                  // 512
  float* scal     = bias_eff + G4;                    // 2
  float* biasp    = scal + 2;                         // 32*512
  int*   srt_g    = (int*)(biasp + NN * G4);          // 128
  int*   off_g    = srt_g + ET;                       // 33

  prep_kernel<<<NN, G4, 0, stream>>>(w_gat, b_gat, W_ih, W_eff, biasp);
  prep2_kernel<<<1, G4, 0, stream>>>(biasp, b_ih, b_hh, w_gat, att_src, att_dst, ei,
                                     bias_eff, scal, srt_g, off_g);
  prep3_kernel<<<G4, 128, 0, stream>>>(W_hh, Wt);
  gatxw_kernel<<<NPOS / 8, 256, 0, stream>>>(x_seq, srt_g, off_g, scal, W_eff, bias_eff, xw);
  lstm_kernel<<<BB, G4, 0, stream>>>(xw, Wt, W_fc, b_fc, (float*)d_out);
}

// Round 9
// 396.094 us; speedup vs baseline: 1.7330x; 1.0357x over previous
//
#include <hip/hip_runtime.h>

#define NN 32      // nodes
#define FF 64      // GAT out features
#define HH 128     // LSTM hidden
#define G4 512     // 4*H
#define BB 32      // batch
#define TT 512     // time steps
#define ET 128     // 96 edges + 32 self loops
#define NPOS (BB*TT)

__device__ __forceinline__ float frcp(float x) { return __builtin_amdgcn_rcpf(x); }

// ---------------- prep: fold GAT linear into LSTM input weights ----------------
__global__ __launch_bounds__(512) void prep_kernel(const float* __restrict__ w_gat,
                                                   const float* __restrict__ b_gat,
                                                   const float* __restrict__ W_ih,
                                                   float* __restrict__ W_eff,
                                                   float* __restrict__ biasp) {
  int j = threadIdx.x;
  int n = blockIdx.x;
  float accw = 0.f, accb = 0.f;
#pragma unroll 8
  for (int f = 0; f < FF; ++f) {
    float wv = W_ih[(n * FF + f) * G4 + j];
    accw = fmaf(w_gat[f], wv, accw);
    accb = fmaf(b_gat[f], wv, accb);
  }
  W_eff[n * G4 + j] = accw;
  biasp[n * G4 + j] = accb;
}

// bias reduce + attention scalars + edge count-sort by dst
__global__ __launch_bounds__(512) void prep2_kernel(const float* __restrict__ biasp,
                                                    const float* __restrict__ b_ih,
                                                    const float* __restrict__ b_hh,
                                                    const float* __restrict__ w_gat,
                                                    const float* __restrict__ att_src,
                                                    const float* __restrict__ att_dst,
                                                    const int* __restrict__ ei,
                                                    float* __restrict__ bias_eff,
                                                    float* __restrict__ scal,
                                                    int* __restrict__ srt_g,
                                                    int* __restrict__ off_g) {
  __shared__ int cnt[NN];
  __shared__ int off[NN + 1];
  __shared__ int srt[ET];
  int j = threadIdx.x;
  if (j < NN) cnt[j] = 0;
  float acc = b_ih[j] + b_hh[j];
#pragma unroll
  for (int n = 0; n < NN; ++n) acc += biasp[n * G4 + j];
  bias_eff[j] = acc;
  if (j == 0) {
    float cs = 0.f, cd = 0.f;
    for (int f = 0; f < FF; ++f) {
      cs = fmaf(w_gat[f], att_src[f], cs);
      cd = fmaf(w_gat[f], att_dst[f], cd);
    }
    scal[0] = cs;
    scal[1] = cd;
  }
  __syncthreads();
  int s = 0, d = 0, tk = 0;
  if (j < ET) {
    if (j < 96) { s = ei[j]; d = ei[96 + j]; }
    else { s = j - 96; d = j - 96; }
    tk = atomicAdd(&cnt[d], 1);
  }
  __syncthreads();
  if (j == 0) {
    off[0] = 0;
    for (int n = 0; n < NN; ++n) off[n + 1] = off[n] + cnt[n];
  }
  __syncthreads();
  if (j < ET) srt[off[d] + tk] = s;
  __syncthreads();
  if (j < ET) srt_g[j] = srt[j];
  if (j < NN + 1) off_g[j] = off[j];
}

// ---------------- prep3: per-thread weight transpose for the asm LSTM ----------------
// Wt[tid*128 + g*32 + kk] = W_hh[(kq*32+kk)][g*128 + r],  tid = r*4+kq
__global__ __launch_bounds__(128) void prep3_kernel(const float* __restrict__ W_hh,
                                                    float* __restrict__ Wt) {
  int tid = blockIdx.x;   // 0..511
  int m = threadIdx.x;    // 0..127
  int r = tid >> 2, kq = tid & 3;
  int g = m >> 5, kk = m & 31;
  Wt[tid * 128 + m] = W_hh[(kq * 32 + kk) * G4 + g * 128 + r];
}

// ---------------- fused GAT + xw: 8 positions per 256-thread block ----------------
__global__ __launch_bounds__(256) void gatxw_kernel(const float* __restrict__ x_seq,
                                                    const int* __restrict__ srt_g,
                                                    const int* __restrict__ off_g,
                                                    const float* __restrict__ scal,
                                                    const float* __restrict__ W_eff,
                                                    const float* __restrict__ bias_eff,
                                                    float* __restrict__ xw) {
  __shared__ int srt[ET];
  __shared__ int offs[NN + 1];
  __shared__ float xs[8 * 32];
  __shared__ float sl[8 * 32];
  int tid = threadIdx.x;
  int posbase = blockIdx.x * 8;
  float we0[NN], we1[NN];
#pragma unroll
  for (int nn = 0; nn < NN; ++nn) {
    we0[nn] = W_eff[nn * G4 + tid];
    we1[nn] = W_eff[nn * G4 + 256 + tid];
  }
  float b0 = bias_eff[tid], b1 = bias_eff[256 + tid];
  if (tid < ET) srt[tid] = srt_g[tid];
  if (tid < NN + 1) offs[tid] = off_g[tid];
  int p = tid >> 5, n = tid & 31;
  xs[tid] = x_seq[posbase * NN + tid];  // coalesced
  __syncthreads();
  float cs = scal[0], cd = scal[1];
  int base = p * 32;
  int e0 = offs[n], e1 = offs[n + 1];
  float xn = xs[base + n];
  float cdxn = cd * xn;
  float m = -3.0e38f;
  for (int e = e0; e < e1; ++e) {
    float ev = fmaf(cs, xs[base + srt[e]], cdxn);
    ev = ev > 0.f ? ev : 0.2f * ev;  // LeakyReLU(0.2)
    m = fmaxf(m, ev);
  }
  float z = 0.f, sa = 0.f;
  for (int e = e0; e < e1; ++e) {
    float xsv = xs[base + srt[e]];
    float ev = fmaf(cs, xsv, cdxn);
    ev = ev > 0.f ? ev : 0.2f * ev;
    float ex = __expf(ev - m);
    z += ex;
    sa = fmaf(ex, xsv, sa);
  }
  sl[p * 32 + n] = sa * frcp(z);
  __syncthreads();
  for (int pp = 0; pp < 8; ++pp) {
    const float4* sp = (const float4*)&sl[pp * 32];
    float a0 = b0, a1 = b1;
#pragma unroll
    for (int q = 0; q < 8; ++q) {
      float4 sv = sp[q];
      a0 = fmaf(sv.x, we0[4 * q], a0);
      a0 = fmaf(sv.y, we0[4 * q + 1], a0);
      a0 = fmaf(sv.z, we0[4 * q + 2], a0);
      a0 = fmaf(sv.w, we0[4 * q + 3], a0);
      a1 = fmaf(sv.x, we1[4 * q], a1);
      a1 = fmaf(sv.y, we1[4 * q + 1], a1);
      a1 = fmaf(sv.z, we1[4 * q + 2], a1);
      a1 = fmaf(sv.w, we1[4 * q + 3], a1);
    }
    size_t row = (size_t)(posbase + pp) * G4;
    xw[row + tid] = a0;
    xw[row + 256 + tid] = a1;
  }
}

// ---------------- LSTM scan: whole t-loop in inline asm ----------------
// R8 over R7: (1) 4-deep x prefetch ring in v[224:227] with vmcnt(3) waits —
// xw stream is HBM (~900cyc); distance 4 phases covers it (R7 distance=1
// exposed ~400cyc/phase). (2) staged lgkmcnt(7..0) waits interleave the 8
// ds_read_b128 with the FMA groups instead of a full drain.
// (R8 macro fix: PK16F/PK16A instead of passing ACC4 as one macro arg.)

#define PK16F(HP, W0, W1, W2, W3) \
  "v_pk_fma_f32 v[216:217], v[" HP "], v[" W0 "], 0\n\t" \
  "v_pk_fma_f32 v[218:219], v[" HP "], v[" W1 "], 0\n\t" \
  "v_pk_fma_f32 v[220:221], v[" HP "], v[" W2 "], 0\n\t" \
  "v_pk_fma_f32 v[222:223], v[" HP "], v[" W3 "], 0\n\t"

#define PK16A(HP, W0, W1, W2, W3) \
  "v_pk_fma_f32 v[216:217], v[" HP "], v[" W0 "], v[216:217]\n\t" \
  "v_pk_fma_f32 v[218:219], v[" HP "], v[" W1 "], v[218:219]\n\t" \
  "v_pk_fma_f32 v[220:221], v[" HP "], v[" W2 "], v[220:221]\n\t" \
  "v_pk_fma_f32 v[222:223], v[" HP "], v[" W3 "], v[222:223]\n\t"

#define PHASE(XSLOT, RD, WR) \
  "ds_read_b128 v[32:35], " RD "\n\t" \
  "ds_read_b128 v[36:39], " RD " offset:16\n\t" \
  "ds_read_b128 v[40:43], " RD " offset:32\n\t" \
  "ds_read_b128 v[44:47], " RD " offset:48\n\t" \
  "ds_read_b128 v[48:51], " RD " offset:64\n\t" \
  "ds_read_b128 v[52:55], " RD " offset:80\n\t" \
  "ds_read_b128 v[56:59], " RD " offset:96\n\t" \
  "ds_read_b128 v[60:63], " RD " offset:112\n\t" \
  "s_waitcnt vmcnt(3)\n\t" \
  "v_mov_b32 v215, " XSLOT "\n\t" \
  "global_load_dword " XSLOT ", v194, %[xwb]\n\t" \
  "v_add_u32 v194, 0x800, v194\n\t" \
  "s_waitcnt lgkmcnt(7)\n\t" \
  PK16F("32:33", "64:65",  "96:97",   "128:129", "160:161") \
  PK16A("34:35", "66:67",  "98:99",   "130:131", "162:163") \
  "s_waitcnt lgkmcnt(6)\n\t" \
  PK16A("36:37", "68:69",  "100:101", "132:133", "164:165") \
  PK16A("38:39", "70:71",  "102:103", "134:135", "166:167") \
  "s_waitcnt lgkmcnt(5)\n\t" \
  PK16A("40:41", "72:73",  "104:105", "136:137", "168:169") \
  PK16A("42:43", "74:75",  "106:107", "138:139", "170:171") \
  "s_waitcnt lgkmcnt(4)\n\t" \
  PK16A("44:45", "76:77",  "108:109", "140:141", "172:173") \
  PK16A("46:47", "78:79",  "110:111", "142:143", "174:175") \
  "s_waitcnt lgkmcnt(3)\n\t" \
  PK16A("48:49", "80:81",  "112:113", "144:145", "176:177") \
  PK16A("50:51", "82:83",  "114:115", "146:147", "178:179") \
  "s_waitcnt lgkmcnt(2)\n\t" \
  PK16A("52:53", "84:85",  "116:117", "148:149", "180:181") \
  PK16A("54:55", "86:87",  "118:119", "150:151", "182:183") \
  "s_waitcnt lgkmcnt(1)\n\t" \
  PK16A("56:57", "88:89",  "120:121", "152:153", "184:185") \
  PK16A("58:59", "90:91",  "122:123", "154:155", "186:187") \
  "s_waitcnt lgkmcnt(0)\n\t" \
  PK16A("60:61", "92:93",  "124:125", "156:157", "188:189") \
  PK16A("62:63", "94:95",  "126:127", "158:159", "190:191") \
  "v_add_f32 v204, v216, v217\n\t" \
  "v_add_f32 v205, v218, v219\n\t" \
  "v_add_f32 v206, v220, v221\n\t" \
  "v_add_f32 v207, v222, v223\n\t" \
  "v_fmac_f32 v204, v215, v200\n\t" \
  "v_fmac_f32 v205, v215, v201\n\t" \
  "v_fmac_f32 v206, v215, v202\n\t" \
  "v_fmac_f32 v207, v215, v203\n\t" \
  "v_add_f32_dpp v204, v204, v204 quad_perm:[1,0,3,2] row_mask:0xf bank_mask:0xf\n\t" \
  "v_add_f32_dpp v205, v205, v205 quad_perm:[1,0,3,2] row_mask:0xf bank_mask:0xf\n\t" \
  "v_add_f32_dpp v206, v206, v206 quad_perm:[1,0,3,2] row_mask:0xf bank_mask:0xf\n\t" \
  "v_add_f32_dpp v207, v207, v207 quad_perm:[1,0,3,2] row_mask:0xf bank_mask:0xf\n\t" \
  "v_add_f32_dpp v204, v204, v204 quad_perm:[2,3,0,1] row_mask:0xf bank_mask:0xf\n\t" \
  "v_add_f32_dpp v205, v205, v205 quad_perm:[2,3,0,1] row_mask:0xf bank_mask:0xf\n\t" \
  "v_add_f32_dpp v206, v206, v206 quad_perm:[2,3,0,1] row_mask:0xf bank_mask:0xf\n\t" \
  "v_add_f32_dpp v207, v207, v207 quad_perm:[2,3,0,1] row_mask:0xf bank_mask:0xf\n\t" \
  "v_mul_f32 v208, 0xbfb8aa3b, v204\n\t" \
  "v_mul_f32 v209, 0xbfb8aa3b, v205\n\t" \
  "v_mul_f32 v210, 0x4038aa3b, v206\n\t" \
  "v_mul_f32 v211, 0xbfb8aa3b, v207\n\t" \
  "v_exp_f32 v208, v208\n\t" \
  "v_exp_f32 v209, v209\n\t" \
  "v_exp_f32 v210, v210\n\t" \
  "v_exp_f32 v211, v211\n\t" \
  "v_add_f32 v208, 1.0, v208\n\t" \
  "v_add_f32 v209, 1.0, v209\n\t" \
  "v_add_f32 v210, 1.0, v210\n\t" \
  "v_add_f32 v211, 1.0, v211\n\t" \
  "v_rcp_f32 v208, v208\n\t" \
  "v_rcp_f32 v209, v209\n\t" \
  "v_rcp_f32 v210, v210\n\t" \
  "v_rcp_f32 v211, v211\n\t" \
  "v_fma_f32 v210, -2.0, v210, 1.0\n\t" \
  "v_mul_f32 v212, v208, v210\n\t" \
  "v_fma_f32 v199, v209, v199, v212\n\t" \
  "v_mul_f32 v214, 0x4038aa3b, v199\n\t" \
  "v_exp_f32 v214, v214\n\t" \
  "s_nop 1\n\t" \
  "v_add_f32 v214, 1.0, v214\n\t" \
  "v_rcp_f32 v214, v214\n\t" \
  "s_nop 1\n\t" \
  "v_fma_f32 v214, -2.0, v214, 1.0\n\t" \
  "v_mul_f32 v213, v211, v214\n\t" \
  "ds_write_b32 " WR ", v213\n\t" \
  "s_waitcnt lgkmcnt(0)\n\t" \
  "s_barrier\n\t"

__global__ __launch_bounds__(512, 2) void lstm_kernel(const float* __restrict__ xw,
                                                      const float* __restrict__ Wt,
                                                      const float* __restrict__ W_fc,
                                                      const float* __restrict__ b_fc,
                                                      float* __restrict__ out) {
  __shared__ __align__(16) float lds[320];  // hA [0,160) floats, hB [160,320)
  int b = blockIdx.x, tid = threadIdx.x;
  int r = tid >> 2, kq = tid & 3;
  if (tid < 320) lds[tid] = 0.f;
  const float* xwb = xw + (size_t)b * TT * G4;
  unsigned xoff0 = (unsigned)((kq * 128 + r) * 4);  // t=0
  unsigned wtoff = (unsigned)(tid * 512);
  unsigned lbase = (unsigned)(uintptr_t)&lds[0];  // LDS aperture is 4GB-aligned
  unsigned rda = lbase + kq * 160;
  unsigned rdb = rda + 640;
  unsigned wra = lbase + (((r >> 5) * 40 + (r & 31)) << 2);
  unsigned wrb = wra + 640;
  float mh0 = (kq == 0) ? 1.f : 0.f;
  float mh1 = (kq == 1) ? 1.f : 0.f;
  float mh2 = (kq == 2) ? 1.f : 0.f;
  float mh3 = (kq == 3) ? 1.f : 0.f;
  __syncthreads();
  asm volatile(
    "v_mov_b32 v194, %[xo]\n\t"
    "v_mov_b32 v195, %[rda]\n\t"
    "v_mov_b32 v196, %[rdb]\n\t"
    "v_mov_b32 v197, %[wra]\n\t"
    "v_mov_b32 v198, %[wrb]\n\t"
    "v_mov_b32 v199, 0\n\t"
    "v_mov_b32 v200, %[m0]\n\t"
    "v_mov_b32 v201, %[m1]\n\t"
    "v_mov_b32 v202, %[m2]\n\t"
    "v_mov_b32 v203, %[m3]\n\t"
    // x prefetch ring: t=0..3 -> v224..v227
    "global_load_dword v224, v194, %[xwb]\n\t"
    "v_add_u32 v194, 0x800, v194\n\t"
    "global_load_dword v225, v194, %[xwb]\n\t"
    "v_add_u32 v194, 0x800, v194\n\t"
    "global_load_dword v226, v194, %[xwb]\n\t"
    "v_add_u32 v194, 0x800, v194\n\t"
    "global_load_dword v227, v194, %[xwb]\n\t"
    "v_add_u32 v194, 0x800, v194\n\t"
    "global_load_dwordx4 v[64:67], %[wto], %[wtb] offset:0\n\t"
    "global_load_dwordx4 v[68:71], %[wto], %[wtb] offset:16\n\t"
    "global_load_dwordx4 v[72:75], %[wto], %[wtb] offset:32\n\t"
    "global_load_dwordx4 v[76:79], %[wto], %[wtb] offset:48\n\t"
    "global_load_dwordx4 v[80:83], %[wto], %[wtb] offset:64\n\t"
    "global_load_dwordx4 v[84:87], %[wto], %[wtb] offset:80\n\t"
    "global_load_dwordx4 v[88:91], %[wto], %[wtb] offset:96\n\t"
    "global_load_dwordx4 v[92:95], %[wto], %[wtb] offset:112\n\t"
    "global_load_dwordx4 v[96:99], %[wto], %[wtb] offset:128\n\t"
    "global_load_dwordx4 v[100:103], %[wto], %[wtb] offset:144\n\t"
    "global_load_dwordx4 v[104:107], %[wto], %[wtb] offset:160\n\t"
    "global_load_dwordx4 v[108:111], %[wto], %[wtb] offset:176\n\t"
    "global_load_dwordx4 v[112:115], %[wto], %[wtb] offset:192\n\t"
    "global_load_dwordx4 v[116:119], %[wto], %[wtb] offset:208\n\t"
    "global_load_dwordx4 v[120:123], %[wto], %[wtb] offset:224\n\t"
    "global_load_dwordx4 v[124:127], %[wto], %[wtb] offset:240\n\t"
    "global_load_dwordx4 v[128:131], %[wto], %[wtb] offset:256\n\t"
    "global_load_dwordx4 v[132:135], %[wto], %[wtb] offset:272\n\t"
    "global_load_dwordx4 v[136:139], %[wto], %[wtb] offset:288\n\t"
    "global_load_dwordx4 v[140:143], %[wto], %[wtb] offset:304\n\t"
    "global_load_dwordx4 v[144:147], %[wto], %[wtb] offset:320\n\t"
    "global_load_dwordx4 v[148:151], %[wto], %[wtb] offset:336\n\t"
    "global_load_dwordx4 v[152:155], %[wto], %[wtb] offset:352\n\t"
    "global_load_dwordx4 v[156:159], %[wto], %[wtb] offset:368\n\t"
    "global_load_dwordx4 v[160:163], %[wto], %[wtb] offset:384\n\t"
    "global_load_dwordx4 v[164:167], %[wto], %[wtb] offset:400\n\t"
    "global_load_dwordx4 v[168:171], %[wto], %[wtb] offset:416\n\t"
    "global_load_dwordx4 v[172:175], %[wto], %[wtb] offset:432\n\t"
    "global_load_dwordx4 v[176:179], %[wto], %[wtb] offset:448\n\t"
    "global_load_dwordx4 v[180:183], %[wto], %[wtb] offset:464\n\t"
    "global_load_dwordx4 v[184:187], %[wto], %[wtb] offset:480\n\t"
    "global_load_dwordx4 v[188:191], %[wto], %[wtb] offset:496\n\t"
    "s_waitcnt vmcnt(4)\n\t"   // wait for the 32 weight loads; keep 4 x-loads in flight
    "s_movk_i32 s20, 0x80\n\t"    // 128 iterations x 4 phases = 512 steps
    "L_lstm_%=:\n\t"
    PHASE("v224", "v195", "v198")   // t%4==0: read A, write B
    PHASE("v225", "v196", "v197")   // t%4==1: read B, write A
    PHASE("v226", "v195", "v198")   // t%4==2: read A, write B
    PHASE("v227", "v196", "v197")   // t%4==3: read B, write A
    "s_sub_u32 s20, s20, 1\n\t"
    "s_cmp_lg_u32 s20, 0\n\t"
    "s_cbranch_scc1 L_lstm_%=\n\t"
    "s_waitcnt vmcnt(0) lgkmcnt(0)\n\t"
    :
    : [xwb]"s"(xwb), [wtb]"s"(Wt), [wto]"v"(wtoff), [xo]"v"(xoff0),
      [rda]"v"(rda), [rdb]"v"(rdb), [wra]"v"(wra), [wrb]"v"(wrb),
      [m0]"v"(mh0), [m1]"v"(mh1), [m2]"v"(mh2), [m3]"v"(mh3)
    : "memory", "scc", "s20",
      "v32","v33","v34","v35","v36","v37","v38","v39",
      "v40","v41","v42","v43","v44","v45","v46","v47",
      "v48","v49","v50","v51","v52","v53","v54","v55",
      "v56","v57","v58","v59","v60","v61","v62","v63",
      "v64","v65","v66","v67","v68","v69","v70","v71",
      "v72","v73","v74","v75","v76","v77","v78","v79",
      "v80","v81","v82","v83","v84","v85","v86","v87",
      "v88","v89","v90","v91","v92","v93","v94","v95",
      "v96","v97","v98","v99","v100","v101","v102","v103",
      "v104","v105","v106","v107","v108","v109","v110","v111",
      "v112","v113","v114","v115","v116","v117","v118","v119",
      "v120","v121","v122","v123","v124","v125","v126","v127",
      "v128","v129","v130","v131","v132","v133","v134","v135",
      "v136","v137","v138","v139","v140","v141","v142","v143",
      "v144","v145","v146","v147","v148","v149","v150","v151",
      "v152","v153","v154","v155","v156","v157","v158","v159",
      "v160","v161","v162","v163","v164","v165","v166","v167",
      "v168","v169","v170","v171","v172","v173","v174","v175",
      "v176","v177","v178","v179","v180","v181","v182","v183",
      "v184","v185","v186","v187","v188","v189","v190","v191",
      "v192","v193","v194","v195","v196","v197","v198","v199",
      "v200","v201","v202","v203","v204","v205","v206","v207",
      "v208","v209","v210","v211","v212","v213","v214","v215",
      "v216","v217","v218","v219","v220","v221","v222","v223",
      "v224","v225","v226","v227");
  __syncthreads();
  // final h (after t=511) is in buffer A: lds[(k>>5)*40 + (k&31)]
  if (tid < 4) {
    float acc = b_fc[tid];
#pragma unroll 8
    for (int k = 0; k < HH; ++k)
      acc = fmaf(lds[(k >> 5) * 40 + (k & 31)], W_fc[k * 4 + tid], acc);
    out[b * 4 + tid] = acc;
  }
}

extern "C" void kernel_launch(void* const* d_in, const int* in_sizes, int n_in,
                              void* d_out, int out_size, void* d_ws, size_t ws_size,
                              hipStream_t stream) {
  const float* x_seq   = (const float*)d_in[0];
  const int*   ei      = (const int*)d_in[1];
  const float* w_gat   = (const float*)d_in[2];
  const float* att_src = (const float*)d_in[3];
  const float* att_dst = (const float*)d_in[4];
  const float* b_gat   = (const float*)d_in[5];
  const float* W_ih    = (const float*)d_in[6];
  const float* W_hh    = (const float*)d_in[7];
  const float* b_ih    = (const float*)d_in[8];
  const float* b_hh    = (const float*)d_in[9];
  const float* W_fc    = (const float*)d_in[10];
  const float* b_fc    = (const float*)d_in[11];

  float* ws = (float*)d_ws;
  float* Wt       = ws;                               // 512*128 = 65536 f (16B-aligned)
  float* xw       = Wt + 65536;                       // (16384+8)*512 f (8 pad rows: 4-deep prefetch)
  float* W_eff    = xw + (size_t)(NPOS + 8) * G4;     // 32*512
  float* bias_eff = W_eff + NN * G4;                  // 512
  float* scal     = bias_eff + G4;                    // 2
  float* biasp    = scal + 2;                         // 32*512
  int*   srt_g    = (int*)(biasp + NN * G4);          // 128
  int*   off_g    = srt_g + ET;                       // 33

  prep_kernel<<<NN, G4, 0, stream>>>(w_gat, b_gat, W_ih, W_eff, biasp);
  prep2_kernel<<<1, G4, 0, stream>>>(biasp, b_ih, b_hh, w_gat, att_src, att_dst, ei,
                                     bias_eff, scal, srt_g, off_g);
  prep3_kernel<<<G4, 128, 0, stream>>>(W_hh, Wt);
  gatxw_kernel<<<NPOS / 8, 256, 0, stream>>>(x_seq, srt_g, off_g, scal, W_eff, bias_eff, xw);
  lstm_kernel<<<BB, G4, 0, stream>>>(xw, Wt, W_fc, b_fc, (float*)d_out);
}